// Round 1
// baseline (534.169 us; speedup 1.0000x reference)
//
#include <hip/hip_runtime.h>

// Problem constants (deterministic from reference _segments()):
//   lengths L_g = 256 + 8g, g = 0..31;  start_g = 256g + 4g(g-1);  N = 12160
#define NTOT 12160
#define EMBD 512
#define ESMD 1280
#define NHEAD 8
#define HD 64
#define NG 32

typedef __attribute__((ext_vector_type(8))) short short8v;   // 8 bf16 = 4 VGPR (MFMA A/B frag)
typedef __attribute__((ext_vector_type(4))) short short4v;   // 4 bf16 = 8 B
typedef __attribute__((ext_vector_type(4))) float floatx4;   // MFMA C/D frag

__device__ inline short f2bf(float f) {
  union { float f; unsigned u; } v; v.f = f;
  unsigned r = v.u + 0x7fffu + ((v.u >> 16) & 1u);   // RNE; inputs are normal floats
  return (short)(r >> 16);
}

// C = A @ W^T + bias.  A: [M=12160, K] (f32 if AKIND==0, bf16 if AKIND==1, row-major)
// W: [512, K] f32 row-major.  OMODE 0: bf16 out [M,512]; 1: bf16 out transposed [512,M];
// 2: f32 out [M,512].  Tiles: 128x128, BK=64, 4 waves in 2x2, each wave 4x4 MFMA subtiles.
template<int AKIND, int OMODE>
__global__ __launch_bounds__(256) void gemm_kernel(
    const void* __restrict__ Ap, const float* __restrict__ W,
    const float* __restrict__ bias, void* __restrict__ Cp, int K)
{
  // LDS stride 72 bf16 = 144 B = 9 x 16B groups -> consecutive rows land on
  // distinct 16B bank-groups (mod 8): b128 reads see only the free 2-way conflict.
  __shared__ short As[128 * 72];
  __shared__ short Bs[128 * 72];
  const int tid = threadIdx.x;
  const int lane = tid & 63, wave = tid >> 6;
  const int l15 = lane & 15, quad = lane >> 4;
  const int wm = (wave >> 1) * 64, wn = (wave & 1) * 64;
  const int row0 = blockIdx.y * 128, col0 = blockIdx.x * 128;

  floatx4 acc[4][4];
  for (int i = 0; i < 4; i++)
    for (int j = 0; j < 4; j++)
      for (int r = 0; r < 4; r++) acc[i][j][r] = 0.f;

  for (int k0 = 0; k0 < K; k0 += 64) {
    if (k0) __syncthreads();
    if (AKIND == 0) {            // f32 A: convert to bf16 while staging
      const float* A = (const float*)Ap;
      for (int p = 0; p < 8; p++) {
        int idx = p * 256 + tid;             // float4 index over 128x16
        int r = idx >> 4, c4 = idx & 15;
        const float4 v = *(const float4*)&A[(size_t)(row0 + r) * K + k0 + c4 * 4];
        short4v sv; sv[0] = f2bf(v.x); sv[1] = f2bf(v.y); sv[2] = f2bf(v.z); sv[3] = f2bf(v.w);
        *(short4v*)&As[r * 72 + c4 * 4] = sv;
      }
    } else {                     // bf16 A: 16B copies
      const short* A = (const short*)Ap;
      for (int p = 0; p < 4; p++) {
        int idx = p * 256 + tid;             // 8-elem index over 128x8
        int r = idx >> 3, c8 = idx & 7;
        short8v v = *(const short8v*)&A[(size_t)(row0 + r) * K + k0 + c8 * 8];
        *(short8v*)&As[r * 72 + c8 * 8] = v;
      }
    }
    for (int p = 0; p < 8; p++) {            // weights always f32
      int idx = p * 256 + tid;
      int r = idx >> 4, c4 = idx & 15;
      const float4 v = *(const float4*)&W[(size_t)(col0 + r) * K + k0 + c4 * 4];
      short4v sv; sv[0] = f2bf(v.x); sv[1] = f2bf(v.y); sv[2] = f2bf(v.z); sv[3] = f2bf(v.w);
      *(short4v*)&Bs[r * 72 + c4 * 4] = sv;
    }
    __syncthreads();

    for (int ks = 0; ks < 64; ks += 32) {
      short8v a[4], b[4];
      for (int mt = 0; mt < 4; mt++)
        a[mt] = *(const short8v*)&As[(wm + mt * 16 + l15) * 72 + ks + quad * 8];
      for (int nt = 0; nt < 4; nt++)
        b[nt] = *(const short8v*)&Bs[(wn + nt * 16 + l15) * 72 + ks + quad * 8];
      for (int mt = 0; mt < 4; mt++)
        for (int nt = 0; nt < 4; nt++)
          acc[mt][nt] = __builtin_amdgcn_mfma_f32_16x16x32_bf16(a[mt], b[nt], acc[mt][nt], 0, 0, 0);
    }
  }

  // Epilogue. C/D layout: col = lane&15, row = quad*4 + reg  [guide m89/m91]
  for (int nt = 0; nt < 4; nt++) {
    int col = col0 + wn + nt * 16 + l15;
    float bv = bias[col];
    for (int mt = 0; mt < 4; mt++) {
      int rowb = row0 + wm + mt * 16 + quad * 4;
      if (OMODE == 0) {
        short* Cs = (short*)Cp;
        for (int r = 0; r < 4; r++)
          Cs[(size_t)(rowb + r) * EMBD + col] = f2bf(acc[mt][nt][r] + bv);
      } else if (OMODE == 1) {   // transposed: 4 consecutive rows -> one 8B store
        short* Cs = (short*)Cp;
        short4v sv;
        for (int r = 0; r < 4; r++) sv[r] = f2bf(acc[mt][nt][r] + bv);
        *(short4v*)&Cs[(size_t)col * NTOT + rowb] = sv;
      } else {
        float* Cf = (float*)Cp;
        for (int r = 0; r < 4; r++)
          Cf[(size_t)(rowb + r) * EMBD + col] = acc[mt][nt][r] + bv;
      }
    }
  }
}

// One wave per (graph, head, 16-query tile). Flash-style online softmax.
// q,k: bf16 [N,512] row-major. v: bf16 [512,N] (transposed). ao: bf16 [N,512].
__global__ __launch_bounds__(64) void attn_kernel(
    const short* __restrict__ qb, const short* __restrict__ kb,
    const short* __restrict__ vt, short* __restrict__ ao)
{
  __shared__ short Ps[16 * 72];              // P tile [16q x 32k], stride 72 (2-way free)
  const int h = blockIdx.y;
  const int bx = blockIdx.x;
  int g = 0;                                  // cumulative tiles Q(g) = 16g + g*g/4
  while (g < NG - 1) { int nx = g + 1; if (bx >= 16 * nx + (nx * nx) / 4) g++; else break; }
  const int qt = bx - (16 * g + (g * g) / 4);
  const int L = 256 + 8 * g;
  const int start = 256 * g + 4 * g * (g - 1);
  const int lane = threadIdx.x;
  const int l15 = lane & 15, quad = lane >> 4;
  const int qmax = start + L - 1;

  int qrow = start + qt * 16 + l15;
  if (qrow > qmax) qrow = qmax;               // clamp: garbage rows never stored
  const size_t qoff = (size_t)qrow * EMBD + h * HD + quad * 8;
  const short8v aq0 = *(const short8v*)&qb[qoff];
  const short8v aq1 = *(const short8v*)&qb[qoff + 32];

  float m[4], lsum[4];
  floatx4 oacc[4];
  for (int r = 0; r < 4; r++) { m[r] = -1e30f; lsum[r] = 0.f; }
  for (int dt = 0; dt < 4; dt++)
    for (int r = 0; r < 4; r++) oacc[dt][r] = 0.f;

  for (int kc = 0; kc < L; kc += 32) {
    floatx4 s[2];
    for (int sub = 0; sub < 2; sub++) {
      int krow = start + kc + sub * 16 + l15;
      if (krow > qmax) krow = qmax;
      size_t ko = (size_t)krow * EMBD + h * HD + quad * 8;
      short8v bk0 = *(const short8v*)&kb[ko];
      short8v bk1 = *(const short8v*)&kb[ko + 32];
      floatx4 c; for (int r = 0; r < 4; r++) c[r] = 0.f;
      c = __builtin_amdgcn_mfma_f32_16x16x32_bf16(aq0, bk0, c, 0, 0, 0);
      c = __builtin_amdgcn_mfma_f32_16x16x32_bf16(aq1, bk1, c, 0, 0, 0);
      s[sub] = c;
    }
    float sv[2][4];
    for (int sub = 0; sub < 2; sub++) {
      bool valid = (kc + sub * 16 + l15) < L;
      for (int r = 0; r < 4; r++) sv[sub][r] = valid ? s[sub][r] * 0.125f : -1e30f;
    }
    float al[4];
    for (int r = 0; r < 4; r++) {
      float cm = fmaxf(sv[0][r], sv[1][r]);   // reduce across the 16-lane col group
      cm = fmaxf(cm, __shfl_xor(cm, 1));
      cm = fmaxf(cm, __shfl_xor(cm, 2));
      cm = fmaxf(cm, __shfl_xor(cm, 4));
      cm = fmaxf(cm, __shfl_xor(cm, 8));
      float mn = fmaxf(m[r], cm);
      al[r] = __expf(m[r] - mn);
      float p0 = __expf(sv[0][r] - mn);
      float p1 = __expf(sv[1][r] - mn);
      m[r] = mn;
      float rs = p0 + p1;
      rs += __shfl_xor(rs, 1); rs += __shfl_xor(rs, 2);
      rs += __shfl_xor(rs, 4); rs += __shfl_xor(rs, 8);
      lsum[r] = lsum[r] * al[r] + rs;
      Ps[(quad * 4 + r) * 72 + l15] = f2bf(p0);        // C-layout -> LDS [q][k]
      Ps[(quad * 4 + r) * 72 + 16 + l15] = f2bf(p1);
    }
    for (int dt = 0; dt < 4; dt++)
      for (int r = 0; r < 4; r++) oacc[dt][r] *= al[r];
    __syncthreads();                                    // 1 wave: just drains lgkm
    short8v pA = *(const short8v*)&Ps[l15 * 72 + quad * 8];  // A-layout read
    int kbase = kc + quad * 8;
    if (kbase > L - 8) kbase = L - 8;                   // p==0 there; avoid OOB
    for (int dt = 0; dt < 4; dt++) {
      const short8v bvv = *(const short8v*)&vt[(size_t)(h * HD + dt * 16 + l15) * NTOT + start + kbase];
      oacc[dt] = __builtin_amdgcn_mfma_f32_16x16x32_bf16(pA, bvv, oacc[dt], 0, 0, 0);
    }
    __syncthreads();                                    // WAR guard before next Ps write
  }
  float inv[4];
  for (int r = 0; r < 4; r++) inv[r] = 1.f / lsum[r];
  for (int dt = 0; dt < 4; dt++)
    for (int r = 0; r < 4; r++) {
      int rl = qt * 16 + quad * 4 + r;
      if (rl < L)
        ao[(size_t)(start + rl) * EMBD + h * HD + dt * 16 + l15] = f2bf(oacc[dt][r] * inv[r]);
    }
}

// y (= d_out, holds proj f32) <- LayerNorm(y + h) * gamma + beta, in place.
__global__ __launch_bounds__(64) void ln_kernel(
    float* __restrict__ y, const float* __restrict__ hres,
    const float* __restrict__ gamma, const float* __restrict__ beta)
{
  const int row = blockIdx.x;
  const int lane = threadIdx.x;
  const size_t base = (size_t)row * EMBD + lane * 8;
  const float4 a0 = *(const float4*)&y[base];
  const float4 a1 = *(const float4*)&y[base + 4];
  const float4 b0 = *(const float4*)&hres[base];
  const float4 b1 = *(const float4*)&hres[base + 4];
  float x[8] = { a0.x + b0.x, a0.y + b0.y, a0.z + b0.z, a0.w + b0.w,
                 a1.x + b1.x, a1.y + b1.y, a1.z + b1.z, a1.w + b1.w };
  float s = 0.f, s2 = 0.f;
  for (int i = 0; i < 8; i++) { s += x[i]; s2 += x[i] * x[i]; }
  for (int off = 1; off < 64; off <<= 1) { s += __shfl_xor(s, off); s2 += __shfl_xor(s2, off); }
  const float mu = s * (1.f / 512.f);
  const float var = s2 * (1.f / 512.f) - mu * mu;
  const float rstd = rsqrtf(var + 1e-5f);
  const float4 g0 = *(const float4*)&gamma[lane * 8];
  const float4 g1 = *(const float4*)&gamma[lane * 8 + 4];
  const float4 e0 = *(const float4*)&beta[lane * 8];
  const float4 e1 = *(const float4*)&beta[lane * 8 + 4];
  const float gg[8] = { g0.x, g0.y, g0.z, g0.w, g1.x, g1.y, g1.z, g1.w };
  const float ee[8] = { e0.x, e0.y, e0.z, e0.w, e1.x, e1.y, e1.z, e1.w };
  float o[8];
  for (int i = 0; i < 8; i++) o[i] = (x[i] - mu) * rstd * gg[i] + ee[i];
  *(float4*)&y[base]     = make_float4(o[0], o[1], o[2], o[3]);
  *(float4*)&y[base + 4] = make_float4(o[4], o[5], o[6], o[7]);
}

extern "C" void kernel_launch(void* const* d_in, const int* in_sizes, int n_in,
                              void* d_out, int out_size, void* d_ws, size_t ws_size,
                              hipStream_t stream)
{
  (void)in_sizes; (void)n_in; (void)out_size; (void)ws_size;
  const float* esm   = (const float*)d_in[0];
  const float* h     = (const float*)d_in[1];
  const float* Wesm  = (const float*)d_in[2];
  const float* besm  = (const float*)d_in[3];
  const float* Wq    = (const float*)d_in[4];
  const float* bq    = (const float*)d_in[5];
  const float* Wk    = (const float*)d_in[6];
  const float* bk    = (const float*)d_in[7];
  const float* Wv    = (const float*)d_in[8];
  const float* bv    = (const float*)d_in[9];
  const float* Wo    = (const float*)d_in[10];
  const float* bo    = (const float*)d_in[11];
  const float* gamma = (const float*)d_in[12];
  const float* beta  = (const float*)d_in[13];

  // ws layout (bytes): hesm[0, 12451840) qb[12451840, ...) kb kb+.. vt
  // ao (attention out) reuses hesm (dead after K/V GEMMs). Total 49,807,360 B.
  char* ws = (char*)d_ws;
  short* hesm = (short*)ws;
  short* qb   = (short*)(ws + 12451840);
  short* kb   = (short*)(ws + 24903680);
  short* vtb  = (short*)(ws + 37355520);
  short* ao   = hesm;
  float* y    = (float*)d_out;

  dim3 ggrid(4, 95), gblk(256);
  gemm_kernel<0, 0><<<ggrid, gblk, 0, stream>>>(esm,  Wesm, besm, hesm, ESMD);
  gemm_kernel<0, 0><<<ggrid, gblk, 0, stream>>>(h,    Wq,   bq,   qb,   EMBD);
  gemm_kernel<1, 0><<<ggrid, gblk, 0, stream>>>(hesm, Wk,   bk,   kb,   EMBD);
  gemm_kernel<1, 1><<<ggrid, gblk, 0, stream>>>(hesm, Wv,   bv,   vtb,  EMBD);
  attn_kernel<<<dim3(768, NHEAD), dim3(64), 0, stream>>>(qb, kb, vtb, ao);
  gemm_kernel<1, 2><<<ggrid, gblk, 0, stream>>>(ao,   Wo,   bo,   y,    EMBD);
  ln_kernel<<<dim3(NTOT), dim3(64), 0, stream>>>(y, h, gamma, beta);
}

// Round 2
// 345.061 us; speedup vs baseline: 1.5480x; 1.5480x over previous
//
#include <hip/hip_runtime.h>

// Problem constants (deterministic from reference _segments()):
//   L_g = 256 + 8g, g=0..31; start_g = 256g + 4g(g-1); N = 12160 = 95*128
#define NTOT 12160
#define EMBD 512
#define ESMD 1280
#define NHEAD 8
#define HD 64
#define NG 32

typedef __attribute__((ext_vector_type(8))) short short8v;   // 8 bf16 (4 VGPR) MFMA A/B frag
typedef __attribute__((ext_vector_type(4))) short short4v;   // 8 B
typedef __attribute__((ext_vector_type(4))) float floatx4;   // MFMA C/D frag

__device__ inline short f2bf(float f) {
  union { float f; unsigned u; } v; v.f = f;
  unsigned r = v.u + 0x7fffu + ((v.u >> 16) & 1u);   // RNE
  return (short)(r >> 16);
}

// async global->LDS, 16 B per lane. LDS dest = wave-uniform base + lane*16.
__device__ inline void gload_lds16(const void* g, void* l) {
  __builtin_amdgcn_global_load_lds((const __attribute__((address_space(1))) void*)g,
                                   (__attribute__((address_space(3))) void*)l, 16, 0, 0);
}

// ---------------- f32 -> bf16 pre-convert (one pass, all tensors) -------------
// group counts (float4 groups): esm 3891200 | h 1556480 | Wesm 163840 | Wq/Wk/Wv/Wo 65536 each
__global__ __launch_bounds__(256) void cvt_kernel(
    const float* __restrict__ esm, const float* __restrict__ h,
    const float* __restrict__ Wesm, const float* __restrict__ Wq,
    const float* __restrict__ Wk, const float* __restrict__ Wv,
    const float* __restrict__ Wo,
    short* __restrict__ esm_b, short* __restrict__ h_b, short* __restrict__ Wesm_b,
    short* __restrict__ Wq_b, short* __restrict__ Wk_b, short* __restrict__ Wv_b,
    short* __restrict__ Wo_b)
{
  int idx = blockIdx.x * 256 + threadIdx.x;        // grid covers 5873664 groups exactly
  const float* src; short* dst; int off;
  if      (idx < 3891200) { src = esm;  dst = esm_b;  off = idx; }
  else if (idx < 5447680) { src = h;    dst = h_b;    off = idx - 3891200; }
  else if (idx < 5611520) { src = Wesm; dst = Wesm_b; off = idx - 5447680; }
  else if (idx < 5677056) { src = Wq;   dst = Wq_b;   off = idx - 5611520; }
  else if (idx < 5742592) { src = Wk;   dst = Wk_b;   off = idx - 5677056; }
  else if (idx < 5808128) { src = Wv;   dst = Wv_b;   off = idx - 5742592; }
  else                    { src = Wo;   dst = Wo_b;   off = idx - 5808128; }
  const float4 v = *(const float4*)&src[(size_t)off * 4];
  short4v s; s[0] = f2bf(v.x); s[1] = f2bf(v.y); s[2] = f2bf(v.z); s[3] = f2bf(v.w);
  *(short4v*)&dst[(size_t)off * 4] = s;
}

// ---------------- GEMM core: C = A @ W^T, 128x128 tile, BK=64 ----------------
// A [M,K] bf16 row-major, W [512,K] bf16 row-major. LDS unpadded [128][64]
// (global_load_lds linear-fill constraint). m97 2-barrier structure.
__device__ inline void gemm_core(const short* __restrict__ A, const short* __restrict__ W,
                                 int K, int row0, int col0,
                                 short* As, short* Bs, floatx4 acc[4][4])
{
  const int tid = threadIdx.x;
  const int lane = tid & 63, wave = tid >> 6;
  const int l15 = lane & 15, quad = lane >> 4;
  const int wm = (wave >> 1) * 64, wn = (wave & 1) * 64;
  const int lrow = lane >> 3;          // 0..7 row within 8-row segment
  const int lcol = (lane & 7) * 8;     // elem col within BK

  for (int k0 = 0; k0 < K; k0 += 64) {
    if (k0) __syncthreads();           // WAR: all waves done reading LDS
    for (int p = 0; p < 4; p++) {      // A tile: 16 KB = 16 x 1KB segments, 4/wave
      int seg = wave * 4 + p;
      gload_lds16(&A[(size_t)(row0 + seg * 8 + lrow) * K + k0 + lcol], &As[seg * 512]);
    }
    for (int p = 0; p < 4; p++) {
      int seg = wave * 4 + p;
      gload_lds16(&W[(size_t)(col0 + seg * 8 + lrow) * K + k0 + lcol], &Bs[seg * 512]);
    }
    __syncthreads();                   // drains vmcnt(0): staging complete
    for (int ks = 0; ks < 64; ks += 32) {
      short8v a[4], b[4];
      for (int mt = 0; mt < 4; mt++)
        a[mt] = *(const short8v*)&As[(wm + mt * 16 + l15) * 64 + ks + quad * 8];
      for (int nt = 0; nt < 4; nt++)
        b[nt] = *(const short8v*)&Bs[(wn + nt * 16 + l15) * 64 + ks + quad * 8];
      for (int mt = 0; mt < 4; mt++)
        for (int nt = 0; nt < 4; nt++)
          acc[mt][nt] = __builtin_amdgcn_mfma_f32_16x16x32_bf16(a[mt], b[nt], acc[mt][nt], 0, 0, 0);
    }
  }
}

// C/D layout: col = lane&15, row = quad*4 + reg  [m89/m91]
__device__ inline void epi_bf16(floatx4 acc[4][4], const float* bias, short* C,
                                int row0, int col0, int wm, int wn, int l15, int quad)
{
  for (int nt = 0; nt < 4; nt++) {
    int col = col0 + wn + nt * 16 + l15;
    float bv = bias[col];
    for (int mt = 0; mt < 4; mt++) {
      int rowb = row0 + wm + mt * 16 + quad * 4;
      for (int r = 0; r < 4; r++)
        C[(size_t)(rowb + r) * EMBD + col] = f2bf(acc[mt][nt][r] + bv);
    }
  }
}

__global__ __launch_bounds__(256) void esm_gemm(
    const short* __restrict__ A, const short* __restrict__ W,
    const float* __restrict__ bias, short* __restrict__ C)
{
  __shared__ short As[128 * 64];
  __shared__ short Bs[128 * 64];
  floatx4 acc[4][4];
  for (int i = 0; i < 4; i++) for (int j = 0; j < 4; j++)
    for (int r = 0; r < 4; r++) acc[i][j][r] = 0.f;
  const int row0 = blockIdx.y * 128, col0 = blockIdx.x * 128;
  gemm_core(A, W, ESMD, row0, col0, As, Bs, acc);
  const int lane = threadIdx.x & 63, wave = threadIdx.x >> 6;
  epi_bf16(acc, bias, C, row0, col0, (wave >> 1) * 64, (wave & 1) * 64, lane & 15, lane >> 4);
}

// Fused Q/K/V: grid.x = 12 (which = x>>2, colblock = x&3). V writes transposed [512,N].
__global__ __launch_bounds__(256) void qkv_gemm(
    const short* __restrict__ hb, const short* __restrict__ hesm,
    const short* __restrict__ Wq, const short* __restrict__ Wk, const short* __restrict__ Wv,
    const float* __restrict__ bq, const float* __restrict__ bk, const float* __restrict__ bv,
    short* __restrict__ qb, short* __restrict__ kb, short* __restrict__ vt)
{
  __shared__ short As[128 * 64];
  __shared__ short Bs[128 * 64];
  const int which = blockIdx.x >> 2;
  const int row0 = blockIdx.y * 128, col0 = (blockIdx.x & 3) * 128;
  const short* A = (which == 0) ? hb : hesm;
  const short* W = (which == 0) ? Wq : (which == 1 ? Wk : Wv);
  const float* bias = (which == 0) ? bq : (which == 1 ? bk : bv);
  floatx4 acc[4][4];
  for (int i = 0; i < 4; i++) for (int j = 0; j < 4; j++)
    for (int r = 0; r < 4; r++) acc[i][j][r] = 0.f;
  gemm_core(A, W, EMBD, row0, col0, As, Bs, acc);
  const int lane = threadIdx.x & 63, wave = threadIdx.x >> 6;
  const int l15 = lane & 15, quad = lane >> 4;
  const int wm = (wave >> 1) * 64, wn = (wave & 1) * 64;
  if (which < 2) {
    epi_bf16(acc, bias, which ? kb : qb, row0, col0, wm, wn, l15, quad);
  } else {                                   // transposed store: 4 rows -> one 8 B store
    for (int nt = 0; nt < 4; nt++) {
      int col = col0 + wn + nt * 16 + l15;
      float bv2 = bias[col];
      for (int mt = 0; mt < 4; mt++) {
        int rowb = row0 + wm + mt * 16 + quad * 4;
        short4v sv;
        for (int r = 0; r < 4; r++) sv[r] = f2bf(acc[mt][nt][r] + bv2);
        *(short4v*)&vt[(size_t)col * NTOT + rowb] = sv;
      }
    }
  }
}

__global__ __launch_bounds__(256) void o_gemm(
    const short* __restrict__ A, const short* __restrict__ W,
    const float* __restrict__ bias, float* __restrict__ C)
{
  __shared__ short As[128 * 64];
  __shared__ short Bs[128 * 64];
  floatx4 acc[4][4];
  for (int i = 0; i < 4; i++) for (int j = 0; j < 4; j++)
    for (int r = 0; r < 4; r++) acc[i][j][r] = 0.f;
  const int row0 = blockIdx.y * 128, col0 = blockIdx.x * 128;
  gemm_core(A, W, EMBD, row0, col0, As, Bs, acc);
  const int lane = threadIdx.x & 63, wave = threadIdx.x >> 6;
  const int l15 = lane & 15, quad = lane >> 4;
  const int wm = (wave >> 1) * 64, wn = (wave & 1) * 64;
  for (int nt = 0; nt < 4; nt++) {
    int col = col0 + wn + nt * 16 + l15;
    float bv = bias[col];
    for (int mt = 0; mt < 4; mt++) {
      int rowb = row0 + wm + mt * 16 + quad * 4;
      for (int r = 0; r < 4; r++)
        C[(size_t)(rowb + r) * EMBD + col] = acc[mt][nt][r] + bv;
    }
  }
}

// ------------- attention: one wave per (graph, head, 16-query tile) ----------
__global__ __launch_bounds__(64) void attn_kernel(
    const short* __restrict__ qb, const short* __restrict__ kb,
    const short* __restrict__ vt, short* __restrict__ ao)
{
  __shared__ short Ps[16 * 72];
  const int h = blockIdx.y;
  const int bx = blockIdx.x;
  int g = 0;                                  // cumulative tiles Q(g) = 16g + g*g/4
  while (g < NG - 1) { int nx = g + 1; if (bx >= 16 * nx + (nx * nx) / 4) g++; else break; }
  const int qt = bx - (16 * g + (g * g) / 4);
  const int L = 256 + 8 * g;
  const int start = 256 * g + 4 * g * (g - 1);
  const int lane = threadIdx.x;
  const int l15 = lane & 15, quad = lane >> 4;
  const int qmax = start + L - 1;

  int qrow = start + qt * 16 + l15;
  if (qrow > qmax) qrow = qmax;
  const size_t qoff = (size_t)qrow * EMBD + h * HD + quad * 8;
  const short8v aq0 = *(const short8v*)&qb[qoff];
  const short8v aq1 = *(const short8v*)&qb[qoff + 32];

  float m[4], lsum[4];
  floatx4 oacc[4];
  for (int r = 0; r < 4; r++) { m[r] = -1e30f; lsum[r] = 0.f; }
  for (int dt = 0; dt < 4; dt++)
    for (int r = 0; r < 4; r++) oacc[dt][r] = 0.f;

  for (int kc = 0; kc < L; kc += 32) {
    floatx4 s[2];
    for (int sub = 0; sub < 2; sub++) {
      int krow = start + kc + sub * 16 + l15;
      if (krow > qmax) krow = qmax;
      size_t ko = (size_t)krow * EMBD + h * HD + quad * 8;
      short8v bk0 = *(const short8v*)&kb[ko];
      short8v bk1 = *(const short8v*)&kb[ko + 32];
      floatx4 c; for (int r = 0; r < 4; r++) c[r] = 0.f;
      c = __builtin_amdgcn_mfma_f32_16x16x32_bf16(aq0, bk0, c, 0, 0, 0);
      c = __builtin_amdgcn_mfma_f32_16x16x32_bf16(aq1, bk1, c, 0, 0, 0);
      s[sub] = c;
    }
    float sv[2][4];
    for (int sub = 0; sub < 2; sub++) {
      bool valid = (kc + sub * 16 + l15) < L;
      for (int r = 0; r < 4; r++) sv[sub][r] = valid ? s[sub][r] * 0.125f : -1e30f;
    }
    float al[4];
    for (int r = 0; r < 4; r++) {
      float cm = fmaxf(sv[0][r], sv[1][r]);
      cm = fmaxf(cm, __shfl_xor(cm, 1));
      cm = fmaxf(cm, __shfl_xor(cm, 2));
      cm = fmaxf(cm, __shfl_xor(cm, 4));
      cm = fmaxf(cm, __shfl_xor(cm, 8));
      float mn = fmaxf(m[r], cm);
      al[r] = __expf(m[r] - mn);
      float p0 = __expf(sv[0][r] - mn);
      float p1 = __expf(sv[1][r] - mn);
      m[r] = mn;
      float rs = p0 + p1;
      rs += __shfl_xor(rs, 1); rs += __shfl_xor(rs, 2);
      rs += __shfl_xor(rs, 4); rs += __shfl_xor(rs, 8);
      lsum[r] = lsum[r] * al[r] + rs;
      Ps[(quad * 4 + r) * 72 + l15] = f2bf(p0);
      Ps[(quad * 4 + r) * 72 + 16 + l15] = f2bf(p1);
    }
    for (int dt = 0; dt < 4; dt++)
      for (int r = 0; r < 4; r++) oacc[dt][r] *= al[r];
    __syncthreads();
    short8v pA = *(const short8v*)&Ps[l15 * 72 + quad * 8];
    int kbase = kc + quad * 8;
    if (kbase > L - 8) kbase = L - 8;
    for (int dt = 0; dt < 4; dt++) {
      const short8v bvv = *(const short8v*)&vt[(size_t)(h * HD + dt * 16 + l15) * NTOT + start + kbase];
      oacc[dt] = __builtin_amdgcn_mfma_f32_16x16x32_bf16(pA, bvv, oacc[dt], 0, 0, 0);
    }
    __syncthreads();
  }
  float inv[4];
  for (int r = 0; r < 4; r++) inv[r] = 1.f / lsum[r];
  for (int dt = 0; dt < 4; dt++)
    for (int r = 0; r < 4; r++) {
      int rl = qt * 16 + quad * 4 + r;
      if (rl < L)
        ao[(size_t)(start + rl) * EMBD + h * HD + dt * 16 + l15] = f2bf(oacc[dt][r] * inv[r]);
    }
}

// y (= d_out f32) <- LayerNorm(y + h) * gamma + beta, in place
__global__ __launch_bounds__(64) void ln_kernel(
    float* __restrict__ y, const float* __restrict__ hres,
    const float* __restrict__ gamma, const float* __restrict__ beta)
{
  const int row = blockIdx.x;
  const int lane = threadIdx.x;
  const size_t base = (size_t)row * EMBD + lane * 8;
  const float4 a0 = *(const float4*)&y[base];
  const float4 a1 = *(const float4*)&y[base + 4];
  const float4 b0 = *(const float4*)&hres[base];
  const float4 b1 = *(const float4*)&hres[base + 4];
  float x[8] = { a0.x + b0.x, a0.y + b0.y, a0.z + b0.z, a0.w + b0.w,
                 a1.x + b1.x, a1.y + b1.y, a1.z + b1.z, a1.w + b1.w };
  float s = 0.f, s2 = 0.f;
  for (int i = 0; i < 8; i++) { s += x[i]; s2 += x[i] * x[i]; }
  for (int off = 1; off < 64; off <<= 1) { s += __shfl_xor(s, off); s2 += __shfl_xor(s2, off); }
  const float mu = s * (1.f / 512.f);
  const float var = s2 * (1.f / 512.f) - mu * mu;
  const float rstd = rsqrtf(var + 1e-5f);
  const float4 g0 = *(const float4*)&gamma[lane * 8];
  const float4 g1 = *(const float4*)&gamma[lane * 8 + 4];
  const float4 e0 = *(const float4*)&beta[lane * 8];
  const float4 e1 = *(const float4*)&beta[lane * 8 + 4];
  const float gg[8] = { g0.x, g0.y, g0.z, g0.w, g1.x, g1.y, g1.z, g1.w };
  const float ee[8] = { e0.x, e0.y, e0.z, e0.w, e1.x, e1.y, e1.z, e1.w };
  float o[8];
  for (int i = 0; i < 8; i++) o[i] = (x[i] - mu) * rstd * gg[i] + ee[i];
  *(float4*)&y[base]     = make_float4(o[0], o[1], o[2], o[3]);
  *(float4*)&y[base + 4] = make_float4(o[4], o[5], o[6], o[7]);
}

extern "C" void kernel_launch(void* const* d_in, const int* in_sizes, int n_in,
                              void* d_out, int out_size, void* d_ws, size_t ws_size,
                              hipStream_t stream)
{
  (void)in_sizes; (void)n_in; (void)out_size; (void)ws_size;
  const float* esm   = (const float*)d_in[0];
  const float* h     = (const float*)d_in[1];
  const float* Wesm  = (const float*)d_in[2];
  const float* besm  = (const float*)d_in[3];
  const float* Wq    = (const float*)d_in[4];
  const float* bq    = (const float*)d_in[5];
  const float* Wk    = (const float*)d_in[6];
  const float* bk    = (const float*)d_in[7];
  const float* Wv    = (const float*)d_in[8];
  const float* bv    = (const float*)d_in[9];
  const float* Wo    = (const float*)d_in[10];
  const float* bo    = (const float*)d_in[11];
  const float* gamma = (const float*)d_in[12];
  const float* beta  = (const float*)d_in[13];

  // ws layout (bytes), total 59,441,152:
  //   esm_b  [0, 31129600)            dead after esm_gemm -> reused for qb, kb
  //   h_b    [31129600, 43581440)     dead after qkv_gemm -> reused for ao
  //   Wesm_b [43581440, 44892160)
  //   Wq_b   [44892160, 45416448)  Wk_b [45416448, 45940736)
  //   Wv_b   [45940736, 46465024)  Wo_b [46465024, 46989312)
  //   hesm   [46989312, 59441152)
  //   vt -> d_out (free scratch until o_gemm overwrites it)
  char* ws = (char*)d_ws;
  short* esm_b  = (short*)ws;
  short* h_b    = (short*)(ws + 31129600);
  short* Wesm_b = (short*)(ws + 43581440);
  short* Wq_b   = (short*)(ws + 44892160);
  short* Wk_b   = (short*)(ws + 45416448);
  short* Wv_b   = (short*)(ws + 45940736);
  short* Wo_b   = (short*)(ws + 46465024);
  short* hesm   = (short*)(ws + 46989312);
  short* qb     = (short*)ws;                  // alias esm_b
  short* kb     = (short*)(ws + 12451840);     // alias esm_b + 12.45MB
  short* ao     = h_b;                         // alias h_b
  short* vt     = (short*)d_out;               // d_out as scratch (24.9 MB >= 12.45)
  float* y      = (float*)d_out;

  cvt_kernel<<<dim3(22944), dim3(256), 0, stream>>>(
      esm, h, Wesm, Wq, Wk, Wv, Wo, esm_b, h_b, Wesm_b, Wq_b, Wk_b, Wv_b, Wo_b);
  esm_gemm<<<dim3(4, 95), dim3(256), 0, stream>>>(esm_b, Wesm_b, besm, hesm);
  qkv_gemm<<<dim3(12, 95), dim3(256), 0, stream>>>(
      h_b, hesm, Wq_b, Wk_b, Wv_b, bq, bk, bv, qb, kb, vt);
  attn_kernel<<<dim3(768, NHEAD), dim3(64), 0, stream>>>(qb, kb, vt, ao);
  o_gemm<<<dim3(4, 95), dim3(256), 0, stream>>>(ao, Wo_b, bo, y);
  ln_kernel<<<dim3(NTOT), dim3(64), 0, stream>>>(y, h, gamma, beta);
}